// Round 14
// baseline (359.860 us; speedup 1.0000x reference)
//
#include <hip/hip_runtime.h>

#define NC_N 100000
#define NV_N 100000
#define E_N  3200000
#define NKEY 200000          // unified key space: [0,NC) cons, [NC,NC+NV) vars
#define SBK  512             // keys per superbucket
#define NSB  391             // ceil(200000/512)
#define SCAP 18432           // per-superbucket capacity (mean 16368, sigma ~128)
#define NBLK_A 400
#define EPB4 2000            // int4 quads per phase-A block (400*2000*4 = E)
#define PAD  (16*NSB)        // base-padding slack for pbuf/elist

typedef __attribute__((ext_vector_type(8))) _Float16  f16x8;
typedef __attribute__((ext_vector_type(4))) float     f32x4;

// ---------------- fused node embedding (cons + vars in one grid) ----------------
// NOTE: must run AFTER k_sbsort — P1/P2 are overlaid by pbuf until then.

__global__ __launch_bounds__(256) void k_embed_all(
    const float* __restrict__ consF, const float* __restrict__ varsF,
    const float* __restrict__ Wc, const float* __restrict__ bc,
    const float* __restrict__ Wv, const float* __restrict__ bv,
    const float* __restrict__ W1c, const float* __restrict__ W1v,
    float* __restrict__ c_emb, float* __restrict__ v_emb,
    _Float16* __restrict__ Pc, _Float16* __restrict__ Pv)
{
    int n = blockIdx.x * blockDim.x + threadIdx.x;
    if (n < NC_N){
        float f0 = consF[2*(size_t)n], f1 = consF[2*(size_t)n + 1];
        float c[32];
        #pragma unroll
        for (int o = 0; o < 32; o++)
            c[o] = fmaxf(fmaf(f0, Wc[o], fmaf(f1, Wc[32 + o], bc[o])), 0.f);
        float4* dc = (float4*)(c_emb + (size_t)n * 32);
        #pragma unroll
        for (int q = 0; q < 8; q++){
            float4 r;
            #pragma unroll
            for (int j = 0; j < 4; j++) (&r.x)[j] = c[q*4 + j];
            dc[q] = r;
        }
        float p[32];
        #pragma unroll
        for (int o = 0; o < 32; o++) p[o] = 0.f;
        #pragma unroll
        for (int k = 0; k < 32; k++){
            float ck = c[k];
            const float* w = W1c + k*32;
            #pragma unroll
            for (int o = 0; o < 32; o++) p[o] = fmaf(ck, w[o], p[o]);
        }
        f16x8* dp = (f16x8*)(Pc + (size_t)n * 32);
        #pragma unroll
        for (int q = 0; q < 4; q++){
            f16x8 r;
            #pragma unroll
            for (int j = 0; j < 8; j++) r[j] = (_Float16)p[q*8 + j];
            dp[q] = r;
        }
    } else {
        int m = n - NC_N;
        if (m >= NV_N) return;
        float x[9];
        #pragma unroll
        for (int k = 0; k < 9; k++) x[k] = varsF[9*(size_t)m + k];
        float v[32];
        #pragma unroll
        for (int o = 0; o < 32; o++){
            float s = bv[o];
            #pragma unroll
            for (int k = 0; k < 9; k++) s = fmaf(x[k], Wv[k*32 + o], s);
            v[o] = fmaxf(s, 0.f);
        }
        float4* dv = (float4*)(v_emb + (size_t)m * 32);
        #pragma unroll
        for (int q = 0; q < 8; q++){
            float4 r;
            #pragma unroll
            for (int j = 0; j < 4; j++) (&r.x)[j] = v[q*4 + j];
            dv[q] = r;
        }
        float p[32];
        #pragma unroll
        for (int o = 0; o < 32; o++) p[o] = 0.f;
        #pragma unroll
        for (int k = 0; k < 32; k++){
            float vk = v[k];
            const float* w = W1v + k*32;
            #pragma unroll
            for (int o = 0; o < 32; o++) p[o] = fmaf(vk, w[o], p[o]);
        }
        f16x8* dp = (f16x8*)(Pv + (size_t)m * 32);
        #pragma unroll
        for (int q = 0; q < 4; q++){
            f16x8 r;
            #pragma unroll
            for (int j = 0; j < 8; j++) r[j] = (_Float16)p[q*8 + j];
            dp[q] = r;
        }
    }
}

// ---------------- deterministic 3-phase counting sort ----------------

// dual LDS hist copies (wave-pair parity) to halve same-bin atomic collisions
__global__ __launch_bounds__(256) void k_sbhist(
    const int* __restrict__ eC, const int* __restrict__ eV, int* __restrict__ hists)
{
    __shared__ int lh[2][NSB];
    int t = threadIdx.x, blk = blockIdx.x;
    int w = (t >> 6) & 1;
    for (int i = t; i < NSB; i += 256){ lh[0][i] = 0; lh[1][i] = 0; }
    __syncthreads();
    const int4* c4 = (const int4*)eC;
    const int4* v4 = (const int4*)eV;
    int qend = (blk + 1) * EPB4;
    for (int i = blk * EPB4 + t; i < qend; i += 256){
        int4 qc = c4[i];
        int4 qv = v4[i];
        #pragma unroll
        for (int j = 0; j < 4; j++){
            atomicAdd(&lh[w][(&qc.x)[j] >> 9], 1);
            atomicAdd(&lh[w][(NC_N + (&qv.x)[j]) >> 9], 1);
        }
    }
    __syncthreads();
    for (int i = t; i < NSB; i += 256) hists[i * NBLK_A + blk] = lh[0][i] + lh[1][i];
}

__global__ __launch_bounds__(512) void k_scanA(
    const int* __restrict__ hists, int* __restrict__ partial, int* __restrict__ total)
{
    __shared__ int s[512];
    int sb = blockIdx.x, t = threadIdx.x;
    int v = (t < NBLK_A) ? hists[sb * NBLK_A + t] : 0;
    s[t] = v;
    __syncthreads();
    #pragma unroll
    for (int d = 1; d < 512; d <<= 1){
        int u = (t >= d) ? s[t - d] : 0;
        __syncthreads();
        s[t] += u;
        __syncthreads();
    }
    if (t < NBLK_A) partial[sb * NBLK_A + t] = s[t] - v;   // exclusive
    if (t == 511) total[sb] = s[511];
}

// scan of PADDED superbucket totals -> 16-entry-aligned bbase; also W2 fp16 hi/lo prep
__global__ __launch_bounds__(512) void k_scanB_w2(
    const int* __restrict__ total, int* __restrict__ bbase,
    const float* __restrict__ W2, _Float16* __restrict__ w2hi, _Float16* __restrict__ w2lo)
{
    __shared__ int s[512];
    int t = threadIdx.x;
    int vp = (t < NSB) ? ((total[t] + 15) & ~15) : 0;
    s[t] = vp;
    __syncthreads();
    #pragma unroll
    for (int d = 1; d < 512; d <<= 1){
        int u = (t >= d) ? s[t - d] : 0;
        __syncthreads();
        s[t] += u;
        __syncthreads();
    }
    if (t < NSB) bbase[t] = s[t] - vp;
    if (t < 128){
        int h = t >> 6, l = t & 63;
        f16x8 vh, vl;
        #pragma unroll
        for (int j = 0; j < 8; j++){
            float w = W2[((l >> 4) * 8 + j) * 32 + h * 16 + (l & 15)];
            _Float16 hi = (_Float16)w;
            vh[j] = hi;
            vl[j] = (_Float16)(w - (float)hi);
        }
        ((f16x8*)w2hi)[t] = vh;
        ((f16x8*)w2lo)[t] = vl;
    }
}

// phase A3: single-writer runs per (block,superbucket); LDS atomics only
__global__ __launch_bounds__(256) void k_sbscatter(
    const int* __restrict__ eC, const int* __restrict__ eV,
    const int* __restrict__ partial, const int* __restrict__ bbase,
    unsigned* __restrict__ pbuf)
{
    __shared__ int lcur[NSB];
    int t = threadIdx.x, blk = blockIdx.x;
    for (int i = t; i < NSB; i += 256) lcur[i] = bbase[i] + partial[i * NBLK_A + blk];
    __syncthreads();
    const int4* c4 = (const int4*)eC;
    const int4* v4 = (const int4*)eV;
    int qend = (blk + 1) * EPB4;
    for (int i = blk * EPB4 + t; i < qend; i += 256){
        int4 qc = c4[i];
        int4 qv = v4[i];
        #pragma unroll
        for (int j = 0; j < 4; j++){
            int kc = (&qc.x)[j], kv = (&qv.x)[j];
            int p1 = atomicAdd(&lcur[kc >> 9], 1);
            pbuf[p1] = ((unsigned)(kc & 511) << 17) | (unsigned)kv;
            int gk = NC_N + kv;
            int p2 = atomicAdd(&lcur[gk >> 9], 1);
            pbuf[p2] = ((unsigned)(gk & 511) << 17) | (unsigned)kc;
        }
    }
}

// phase B: one block per superbucket; 512-bin hist/scan -> cnt/offs; LDS-staged
// permute; uint4 reads + int4 COALESCED elist write (bases 16-entry aligned).
__global__ __launch_bounds__(256) void k_sbsort(
    const unsigned* __restrict__ pbuf, const int* __restrict__ bbase,
    const int* __restrict__ total, int* __restrict__ cnt,
    int* __restrict__ offs, int* __restrict__ elist)
{
    __shared__ int sout[SCAP];
    __shared__ int hist[SBK];
    __shared__ int cur[SBK];
    __shared__ int ts[256];
    int b = blockIdx.x, t = threadIdx.x;
    int base = bbase[b], n = total[b];
    if (n > SCAP) n = SCAP;             // safety clamp (never hit for this input)
    int nq = n >> 2;
    const uint4* p4 = (const uint4*)(pbuf + base);
    for (int i = t; i < SBK; i += 256) hist[i] = 0;
    __syncthreads();
    for (int i = t; i < nq; i += 256){
        uint4 q = p4[i];
        atomicAdd(&hist[q.x >> 17], 1);
        atomicAdd(&hist[q.y >> 17], 1);
        atomicAdd(&hist[q.z >> 17], 1);
        atomicAdd(&hist[q.w >> 17], 1);
    }
    for (int i = (nq << 2) + t; i < n; i += 256) atomicAdd(&hist[pbuf[base + i] >> 17], 1);
    __syncthreads();
    int h0 = hist[2*t], h1 = hist[2*t+1];
    int tsum = h0 + h1;
    ts[t] = tsum;
    __syncthreads();
    #pragma unroll
    for (int d = 1; d < 256; d <<= 1){
        int u = (t >= d) ? ts[t - d] : 0;
        __syncthreads();
        ts[t] += u;
        __syncthreads();
    }
    int e0 = ts[t] - tsum;
    int e1 = e0 + h0;
    cur[2*t]   = e0;                    // LOCAL offsets into sout
    cur[2*t+1] = e1;
    int g = b * SBK + 2*t;
    if (g   < NKEY){ cnt[g]   = h0; offs[g]   = base + e0; }
    if (g+1 < NKEY){ cnt[g+1] = h1; offs[g+1] = base + e1; }
    __syncthreads();
    for (int i = t; i < nq; i += 256){
        uint4 q = p4[i];
        #pragma unroll
        for (int j = 0; j < 4; j++){
            unsigned p = (&q.x)[j];
            int pos = atomicAdd(&cur[p >> 17], 1);
            sout[pos] = (int)(p & 0x1FFFFu);
        }
    }
    for (int i = (nq << 2) + t; i < n; i += 256){
        unsigned p = pbuf[base + i];
        int pos = atomicAdd(&cur[p >> 17], 1);
        sout[pos] = (int)(p & 0x1FFFFu);
    }
    __syncthreads();
    int4* o4 = (int4*)(elist + base);
    for (int i = t; i < nq; i += 256){
        int4 w;
        w.x = sout[4*i]; w.y = sout[4*i+1]; w.z = sout[4*i+2]; w.w = sout[4*i+3];
        o4[i] = w;
    }
    for (int i = (nq << 2) + t; i < n; i += 256) elist[base + i] = sout[i];
}

// ---------------- edge main loop (round-9 proven form), shared by both passes --
// h_e = relu(pc16 + Pvar[other_e]) in PACKED fp16; G = H @ W2 via f16 MFMA with
// fp16 hi/lo weight split; returns per-lane acc (lane l<16: col l; 16..31: col 16+(l&15)... 
// i.e. acc0 -> col (l&15), acc1 -> col 16+(l&15); after shfl-reduce lane l<32 holds col l.
__device__ __forceinline__ void edge_core(
    const _Float16* __restrict__ Pconst, const _Float16* __restrict__ Pvar,
    const int* __restrict__ offs, const int* __restrict__ cnt,
    const int* __restrict__ elist,
    const _Float16* __restrict__ w2hi, const _Float16* __restrict__ w2lo,
    const float* __restrict__ b1, const float* __restrict__ b2,
    int wid, int l, float& racc0, float& racc1)
{
    int row = l & 15;     // A-row (edge within tile) / C-col
    int kg  = l >> 4;     // k-chunk group

    f16x8 wh0 = ((const f16x8*)w2hi)[l];
    f16x8 wh1 = ((const f16x8*)w2hi)[64 + l];
    f16x8 wl0 = ((const f16x8*)w2lo)[l];
    f16x8 wl1 = ((const f16x8*)w2lo)[64 + l];
    float b2a = b2[row];
    float b2b = b2[16 + row];

    // pc16 = fp16(Pconst_row + b1), packed once per wave
    f16x8 pcv = *(const f16x8*)(Pconst + (size_t)wid * 32 + kg * 8);
    const float* pb = b1 + kg * 8;
    f16x8 pc16;
    #pragma unroll
    for (int j = 0; j < 8; j++) pc16[j] = (_Float16)((float)pcv[j] + pb[j]);
    const f16x8 zero = {};

    int start = offs[wid], deg = cnt[wid];
    float acc0 = 0.f, acc1 = 0.f;
    int nfull = deg >> 4;

    for (int t = 0; t < nfull; t++){
        int other = elist[start + t * 16 + row];
        f16x8 av = *(const f16x8*)(Pvar + (size_t)other * 32 + kg * 8);
        f16x8 h = __builtin_elementwise_max(av + pc16, zero);   // v_pk_add/max_f16

        f32x4 c0 = {0.f, 0.f, 0.f, 0.f}, c1 = {0.f, 0.f, 0.f, 0.f};
        c0 = __builtin_amdgcn_mfma_f32_16x16x32_f16(h, wh0, c0, 0, 0, 0);
        c0 = __builtin_amdgcn_mfma_f32_16x16x32_f16(h, wl0, c0, 0, 0, 0);
        c1 = __builtin_amdgcn_mfma_f32_16x16x32_f16(h, wh1, c1, 0, 0, 0);
        c1 = __builtin_amdgcn_mfma_f32_16x16x32_f16(h, wl1, c1, 0, 0, 0);

        #pragma unroll
        for (int rr = 0; rr < 4; rr++){
            acc0 += fmaxf(c0[rr] + b2a, 0.f);
            acc1 += fmaxf(c1[rr] + b2b, 0.f);
        }
    }
    if (deg & 15){                       // predicated tail tile
        int r  = nfull * 16 + row;
        int rc = (r < deg) ? r : (deg - 1);
        int other = elist[start + rc];
        f16x8 av = *(const f16x8*)(Pvar + (size_t)other * 32 + kg * 8);
        f16x8 h = __builtin_elementwise_max(av + pc16, zero);

        f32x4 c0 = {0.f, 0.f, 0.f, 0.f}, c1 = {0.f, 0.f, 0.f, 0.f};
        c0 = __builtin_amdgcn_mfma_f32_16x16x32_f16(h, wh0, c0, 0, 0, 0);
        c0 = __builtin_amdgcn_mfma_f32_16x16x32_f16(h, wl0, c0, 0, 0, 0);
        c1 = __builtin_amdgcn_mfma_f32_16x16x32_f16(h, wh1, c1, 0, 0, 0);
        c1 = __builtin_amdgcn_mfma_f32_16x16x32_f16(h, wl1, c1, 0, 0, 0);

        #pragma unroll
        for (int rr = 0; rr < 4; rr++){
            int er = nfull * 16 + kg * 4 + rr;   // C row = edge index
            if (er < deg){
                acc0 += fmaxf(c0[rr] + b2a, 0.f);
                acc1 += fmaxf(c1[rr] + b2b, 0.f);
            }
        }
    }

    acc0 += __shfl_xor(acc0, 16, 64);
    acc0 += __shfl_xor(acc0, 32, 64);
    acc1 += __shfl_xor(acc1, 16, 64);
    acc1 += __shfl_xor(acc1, 32, 64);
    racc0 = acc0; racc1 = acc1;
}

// ---------------- pass 1: edge aggregation + FUSED cons-representation --------
// After reduce, lane l<32 holds seg-sum col l. Wave-local LDS broadcast (own row
// only -> NO barriers) computes out_c = relu([acc,c]@Wcr+bcr) in-place over cemb
// and P2 = out_c @ W1c (fp16). Grid is exactly n/4 blocks: no early-exit waves.
__global__ __launch_bounds__(256) void k_edge_p1(
    const _Float16* __restrict__ Pconst, const _Float16* __restrict__ Pvar,
    const int* __restrict__ offs, const int* __restrict__ cnt,
    const int* __restrict__ elist,
    const _Float16* __restrict__ w2hi, const _Float16* __restrict__ w2lo,
    const float* __restrict__ b1, const float* __restrict__ b2,
    float* __restrict__ cemb,
    const float* __restrict__ Wcr, const float* __restrict__ bcr,
    const float* __restrict__ W1c, _Float16* __restrict__ P)
{
    __shared__ float sacc[4][32];
    __shared__ float scm[4][32];
    int wid = (blockIdx.x * 256 + threadIdx.x) >> 6;
    int l   = threadIdx.x & 63;
    int w   = threadIdx.x >> 6;
    float acc0, acc1;
    edge_core(Pconst, Pvar, offs, cnt, elist, w2hi, w2lo, b1, b2, wid, l, acc0, acc1);

    size_t nb = (size_t)wid * 32;
    int lm = l & 31;
    if (l < 16)      sacc[w][l] = acc0;
    else if (l < 32) sacc[w][l] = acc1;
    if (l < 32)      scm[w][l]  = cemb[nb + l];
    // wave-internal LDS: compiler orders via lgkmcnt; no cross-wave sharing.
    float h = bcr[lm];
    #pragma unroll
    for (int q = 0; q < 8; q++){
        f32x4 va = *(const f32x4*)&sacc[w][q*4];
        #pragma unroll
        for (int j = 0; j < 4; j++) h = fmaf(va[j], Wcr[(q*4 + j)*32 + lm], h);
    }
    #pragma unroll
    for (int q = 0; q < 8; q++){
        f32x4 vc = *(const f32x4*)&scm[w][q*4];
        #pragma unroll
        for (int j = 0; j < 4; j++) h = fmaf(vc[j], Wcr[(32 + q*4 + j)*32 + lm], h);
    }
    h = fmaxf(h, 0.f);
    if (l < 32) cemb[nb + l] = h;
    if (l < 32) sacc[w][l] = h;          // wave-lockstep: prior reads complete
    float p = 0.f;
    #pragma unroll
    for (int q = 0; q < 8; q++){
        f32x4 vh = *(const f32x4*)&sacc[w][q*4];
        #pragma unroll
        for (int j = 0; j < 4; j++) p = fmaf(vh[j], W1c[(q*4 + j)*32 + lm], p);
    }
    if (l < 32) P[nb + l] = (_Float16)p;
}

// ---------------- pass 2: edge aggregation + FUSED output module --------------
// out_v = relu([acc,v]@Wvr+bvr); h=relu(@Wo1+bo1); h=relu(@Wo2+bo2); @Wo3+bo3.
__global__ __launch_bounds__(256) void k_edge_p2(
    const _Float16* __restrict__ Pconst, const _Float16* __restrict__ Pvar,
    const int* __restrict__ offs, const int* __restrict__ cnt,
    const int* __restrict__ elist,
    const _Float16* __restrict__ w2hi, const _Float16* __restrict__ w2lo,
    const float* __restrict__ b1, const float* __restrict__ b2,
    const float* __restrict__ vemb,
    const float* __restrict__ Wvr, const float* __restrict__ bvr,
    const float* __restrict__ Wo1, const float* __restrict__ bo1,
    const float* __restrict__ Wo2, const float* __restrict__ bo2,
    const float* __restrict__ Wo3, const float* __restrict__ bo3,
    float* __restrict__ out)
{
    __shared__ float sA[4][32];
    __shared__ float sB[4][32];
    int wid = (blockIdx.x * 256 + threadIdx.x) >> 6;
    int l   = threadIdx.x & 63;
    int w   = threadIdx.x >> 6;
    float acc0, acc1;
    edge_core(Pconst, Pvar, offs, cnt, elist, w2hi, w2lo, b1, b2, wid, l, acc0, acc1);

    size_t nb = (size_t)wid * 32;
    int lm = l & 31;
    if (l < 16)      sA[w][l] = acc0;
    else if (l < 32) sA[w][l] = acc1;
    if (l < 32)      sB[w][l] = vemb[nb + l];
    float a = bvr[lm];
    #pragma unroll
    for (int q = 0; q < 8; q++){
        f32x4 va = *(const f32x4*)&sA[w][q*4];
        #pragma unroll
        for (int j = 0; j < 4; j++) a = fmaf(va[j], Wvr[(q*4 + j)*32 + lm], a);
    }
    #pragma unroll
    for (int q = 0; q < 8; q++){
        f32x4 vv = *(const f32x4*)&sB[w][q*4];
        #pragma unroll
        for (int j = 0; j < 4; j++) a = fmaf(vv[j], Wvr[(32 + q*4 + j)*32 + lm], a);
    }
    a = fmaxf(a, 0.f);
    if (l < 32) sA[w][l] = a;            // wave-lockstep reuse
    float c = bo1[lm];
    #pragma unroll
    for (int q = 0; q < 8; q++){
        f32x4 va = *(const f32x4*)&sA[w][q*4];
        #pragma unroll
        for (int j = 0; j < 4; j++) c = fmaf(va[j], Wo1[(q*4 + j)*32 + lm], c);
    }
    c = fmaxf(c, 0.f);
    if (l < 32) sB[w][l] = c;
    float d = bo2[lm];
    #pragma unroll
    for (int q = 0; q < 8; q++){
        f32x4 vc = *(const f32x4*)&sB[w][q*4];
        #pragma unroll
        for (int j = 0; j < 4; j++) d = fmaf(vc[j], Wo2[(q*4 + j)*32 + lm], d);
    }
    float s = (l < 32) ? fmaxf(d, 0.f) * Wo3[lm] : 0.f;
    s += __shfl_xor(s, 1, 32);
    s += __shfl_xor(s, 2, 32);
    s += __shfl_xor(s, 4, 32);
    s += __shfl_xor(s, 8, 32);
    s += __shfl_xor(s, 16, 32);
    if (l == 0) out[wid] = s + bo3[0];
}

// ---------------- launch ----------------

extern "C" void kernel_launch(void* const* d_in, const int* in_sizes, int n_in,
                              void* d_out, int out_size, void* d_ws, size_t ws_size,
                              hipStream_t stream)
{
    (void)in_sizes; (void)n_in; (void)out_size; (void)ws_size;
    const float* consF = (const float*)d_in[0];
    const float* varsF = (const float*)d_in[1];
    const int*   eidx  = (const int*)d_in[2];
    const int*   eCons = eidx;
    const int*   eVars = eidx + E_N;

    const float* Wc  = (const float*)d_in[3],  *bc  = (const float*)d_in[4];
    const float* Wv  = (const float*)d_in[5],  *bv  = (const float*)d_in[6];
    const float* Wj1 = (const float*)d_in[7],  *bj1 = (const float*)d_in[8];
    const float* Wj2 = (const float*)d_in[9],  *bj2 = (const float*)d_in[10];
    const float* Wcr = (const float*)d_in[11], *bcr = (const float*)d_in[12];
    const float* Wvr = (const float*)d_in[13], *bvr = (const float*)d_in[14];
    const float* Wo1 = (const float*)d_in[15], *bo1 = (const float*)d_in[16];
    const float* Wo2 = (const float*)d_in[17], *bo2 = (const float*)d_in[18];
    const float* Wo3 = (const float*)d_in[19], *bo3 = (const float*)d_in[20];

    const size_t NT = (size_t)100000 * 32;
    float*    c_emb = (float*)d_ws;             // 12.8 MB; -> out_c in place
    float*    v_emb = c_emb + NT;               // 12.8 MB
    _Float16* P1    = (_Float16*)(v_emb + NT);  // 6.4 MB fp16 (var pass1 / const pass2)
    _Float16* P2    = P1 + NT;                  // 6.4 MB fp16 (const pass1 / var pass2)
    float*    spare = (float*)(P2 + NT);        // 12.8 MB (pbuf backing only now)
    unsigned* pbuf  = (unsigned*)P1;            // overlay 25.6MB+PAD over P1..spare+PAD
    int*   cnt     = (int*)(spare + NT) + PAD;  // [NKEY]  (PAD ints reserved for pbuf tail)
    int*   offs    = cnt + NKEY;                // [NKEY]
    int*   hists   = offs + NKEY;               // [NSB*NBLK_A]
    int*   partial = hists + NSB*NBLK_A;        // [NSB*NBLK_A]
    int*   total   = partial + NSB*NBLK_A;      // [NSB]
    int*   bbase   = total + NSB;               // [NSB]
    int*   elist   = bbase + NSB;               // [2E + PAD]
    _Float16* w2hi = (_Float16*)(elist + 2*E_N + PAD);  // [2][64][8]
    _Float16* w2lo = w2hi + 1024;

    const float* W1c = Wj1;                     // rows 0..31  (cons/out_c side)
    const float* W1v = Wj1 + 32*32;             // rows 32..63 (vars side)

    // --- deterministic 3-phase counting sort for BOTH directions ---
    k_sbhist<<<dim3(NBLK_A), dim3(256), 0, stream>>>(eCons, eVars, hists);
    k_scanA<<<dim3(NSB), dim3(512), 0, stream>>>(hists, partial, total);
    k_scanB_w2<<<dim3(1), dim3(512), 0, stream>>>(total, bbase, Wj2, w2hi, w2lo);
    k_sbscatter<<<dim3(NBLK_A), dim3(256), 0, stream>>>(eCons, eVars, partial, bbase, pbuf);
    k_sbsort<<<dim3(NSB), dim3(256), 0, stream>>>(pbuf, bbase, total, cnt, offs, elist);

    // --- fused embeddings + layer-1 hoist (P1/P2 overwrite: pbuf is dead now) ---
    k_embed_all<<<dim3(782), dim3(256), 0, stream>>>(consF, varsF, Wc, bc, Wv, bv,
                                                     W1c, W1v, c_emb, v_emb, P2, P1);

    // ---- pass 1: edges -> constraints + fused cons-representation ----
    k_edge_p1<<<dim3(25000), dim3(256), 0, stream>>>(
        P2, P1, offs, cnt, elist, w2hi, w2lo, bj1, bj2,
        c_emb, Wcr, bcr, W1c, P2);

    // ---- pass 2: edges -> variables + fused output module ----
    k_edge_p2<<<dim3(25000), dim3(256), 0, stream>>>(
        P1, P2, offs + NC_N, cnt + NC_N, elist, w2hi, w2lo, bj1, bj2,
        v_emb, Wvr, bvr, Wo1, bo1, Wo2, bo2, Wo3, bo3, (float*)d_out);
}

// Round 15
// 306.260 us; speedup vs baseline: 1.1750x; 1.1750x over previous
//
#include <hip/hip_runtime.h>

#define NC_N 100000
#define NV_N 100000
#define E_N  3200000
#define NKEY 200000          // unified key space: [0,NC) cons, [NC,NC+NV) vars
#define SBK  256             // keys per superbucket
#define NSB  782             // ceil(200000/256)
#define SCAP 9216            // per-superbucket capacity (mean 8184, sigma ~90)
#define NBLK_A 400
#define EPB4 2000            // int4 quads per phase-A block (400*2000*4 = E)
#define PAD  (16*NSB)        // base-padding slack for pbuf/elist

typedef __attribute__((ext_vector_type(8))) _Float16  f16x8;
typedef __attribute__((ext_vector_type(4))) float     f32x4;

// ---------------- fused node embedding (cons + vars in one grid) ----------------
// NOTE: must run AFTER k_sbsort — P1/P2 are overlaid by pbuf until then.
// c_emb/v_emb stored fp16 (math in f32 registers).

__global__ __launch_bounds__(256) void k_embed_all(
    const float* __restrict__ consF, const float* __restrict__ varsF,
    const float* __restrict__ Wc, const float* __restrict__ bc,
    const float* __restrict__ Wv, const float* __restrict__ bv,
    const float* __restrict__ W1c, const float* __restrict__ W1v,
    _Float16* __restrict__ c_emb, _Float16* __restrict__ v_emb,
    _Float16* __restrict__ Pc, _Float16* __restrict__ Pv)
{
    int n = blockIdx.x * blockDim.x + threadIdx.x;
    if (n < NC_N){
        float f0 = consF[2*(size_t)n], f1 = consF[2*(size_t)n + 1];
        float c[32];
        #pragma unroll
        for (int o = 0; o < 32; o++)
            c[o] = fmaxf(fmaf(f0, Wc[o], fmaf(f1, Wc[32 + o], bc[o])), 0.f);
        f16x8* dc = (f16x8*)(c_emb + (size_t)n * 32);
        #pragma unroll
        for (int q = 0; q < 4; q++){
            f16x8 r;
            #pragma unroll
            for (int j = 0; j < 8; j++) r[j] = (_Float16)c[q*8 + j];
            dc[q] = r;
        }
        float p[32];
        #pragma unroll
        for (int o = 0; o < 32; o++) p[o] = 0.f;
        #pragma unroll
        for (int k = 0; k < 32; k++){
            float ck = c[k];
            const float* w = W1c + k*32;
            #pragma unroll
            for (int o = 0; o < 32; o++) p[o] = fmaf(ck, w[o], p[o]);
        }
        f16x8* dp = (f16x8*)(Pc + (size_t)n * 32);
        #pragma unroll
        for (int q = 0; q < 4; q++){
            f16x8 r;
            #pragma unroll
            for (int j = 0; j < 8; j++) r[j] = (_Float16)p[q*8 + j];
            dp[q] = r;
        }
    } else {
        int m = n - NC_N;
        if (m >= NV_N) return;
        float x[9];
        #pragma unroll
        for (int k = 0; k < 9; k++) x[k] = varsF[9*(size_t)m + k];
        float v[32];
        #pragma unroll
        for (int o = 0; o < 32; o++){
            float s = bv[o];
            #pragma unroll
            for (int k = 0; k < 9; k++) s = fmaf(x[k], Wv[k*32 + o], s);
            v[o] = fmaxf(s, 0.f);
        }
        f16x8* dv = (f16x8*)(v_emb + (size_t)m * 32);
        #pragma unroll
        for (int q = 0; q < 4; q++){
            f16x8 r;
            #pragma unroll
            for (int j = 0; j < 8; j++) r[j] = (_Float16)v[q*8 + j];
            dv[q] = r;
        }
        float p[32];
        #pragma unroll
        for (int o = 0; o < 32; o++) p[o] = 0.f;
        #pragma unroll
        for (int k = 0; k < 32; k++){
            float vk = v[k];
            const float* w = W1v + k*32;
            #pragma unroll
            for (int o = 0; o < 32; o++) p[o] = fmaf(vk, w[o], p[o]);
        }
        f16x8* dp = (f16x8*)(Pv + (size_t)m * 32);
        #pragma unroll
        for (int q = 0; q < 4; q++){
            f16x8 r;
            #pragma unroll
            for (int j = 0; j < 8; j++) r[j] = (_Float16)p[q*8 + j];
            dp[q] = r;
        }
    }
}

// ---------------- deterministic 3-phase counting sort ----------------

// dual LDS hist copies (wave-pair parity) to halve same-bin atomic collisions
__global__ __launch_bounds__(256) void k_sbhist(
    const int* __restrict__ eC, const int* __restrict__ eV, int* __restrict__ hists)
{
    __shared__ int lh[2][NSB];
    int t = threadIdx.x, blk = blockIdx.x;
    int w = (t >> 6) & 1;
    for (int i = t; i < NSB; i += 256){ lh[0][i] = 0; lh[1][i] = 0; }
    __syncthreads();
    const int4* c4 = (const int4*)eC;
    const int4* v4 = (const int4*)eV;
    int qend = (blk + 1) * EPB4;
    for (int i = blk * EPB4 + t; i < qend; i += 256){
        int4 qc = c4[i];
        int4 qv = v4[i];
        #pragma unroll
        for (int j = 0; j < 4; j++){
            atomicAdd(&lh[w][(&qc.x)[j] >> 8], 1);
            atomicAdd(&lh[w][(NC_N + (&qv.x)[j]) >> 8], 1);
        }
    }
    __syncthreads();
    for (int i = t; i < NSB; i += 256) hists[i * NBLK_A + blk] = lh[0][i] + lh[1][i];
}

__global__ __launch_bounds__(512) void k_scanA(
    const int* __restrict__ hists, int* __restrict__ partial, int* __restrict__ total)
{
    __shared__ int s[512];
    int sb = blockIdx.x, t = threadIdx.x;
    int v = (t < NBLK_A) ? hists[sb * NBLK_A + t] : 0;
    s[t] = v;
    __syncthreads();
    #pragma unroll
    for (int d = 1; d < 512; d <<= 1){
        int u = (t >= d) ? s[t - d] : 0;
        __syncthreads();
        s[t] += u;
        __syncthreads();
    }
    if (t < NBLK_A) partial[sb * NBLK_A + t] = s[t] - v;   // exclusive
    if (t == 511) total[sb] = s[511];
}

// scan of PADDED superbucket totals -> 16-entry-aligned bbase; also W2 fp16 hi/lo prep
__global__ __launch_bounds__(1024) void k_scanB_w2(
    const int* __restrict__ total, int* __restrict__ bbase,
    const float* __restrict__ W2, _Float16* __restrict__ w2hi, _Float16* __restrict__ w2lo)
{
    __shared__ int s[1024];
    int t = threadIdx.x;
    int vp = (t < NSB) ? ((total[t] + 15) & ~15) : 0;
    s[t] = vp;
    __syncthreads();
    #pragma unroll
    for (int d = 1; d < 1024; d <<= 1){
        int u = (t >= d) ? s[t - d] : 0;
        __syncthreads();
        s[t] += u;
        __syncthreads();
    }
    if (t < NSB) bbase[t] = s[t] - vp;
    if (t < 128){
        int h = t >> 6, l = t & 63;
        f16x8 vh, vl;
        #pragma unroll
        for (int j = 0; j < 8; j++){
            float w = W2[((l >> 4) * 8 + j) * 32 + h * 16 + (l & 15)];
            _Float16 hi = (_Float16)w;
            vh[j] = hi;
            vl[j] = (_Float16)(w - (float)hi);
        }
        ((f16x8*)w2hi)[t] = vh;
        ((f16x8*)w2lo)[t] = vl;
    }
}

// phase A3: single-writer runs per (block,superbucket); LDS atomics only
__global__ __launch_bounds__(256) void k_sbscatter(
    const int* __restrict__ eC, const int* __restrict__ eV,
    const int* __restrict__ partial, const int* __restrict__ bbase,
    unsigned* __restrict__ pbuf)
{
    __shared__ int lcur[NSB];
    int t = threadIdx.x, blk = blockIdx.x;
    for (int i = t; i < NSB; i += 256) lcur[i] = bbase[i] + partial[i * NBLK_A + blk];
    __syncthreads();
    const int4* c4 = (const int4*)eC;
    const int4* v4 = (const int4*)eV;
    int qend = (blk + 1) * EPB4;
    for (int i = blk * EPB4 + t; i < qend; i += 256){
        int4 qc = c4[i];
        int4 qv = v4[i];
        #pragma unroll
        for (int j = 0; j < 4; j++){
            int kc = (&qc.x)[j], kv = (&qv.x)[j];
            int p1 = atomicAdd(&lcur[kc >> 8], 1);
            pbuf[p1] = ((unsigned)(kc & 255) << 17) | (unsigned)kv;
            int gk = NC_N + kv;
            int p2 = atomicAdd(&lcur[gk >> 8], 1);
            pbuf[p2] = ((unsigned)(gk & 255) << 17) | (unsigned)kc;
        }
    }
}

// phase B: one block per superbucket; SINGLE pbuf read staged into LDS sin[];
// 256-bin hist/scan -> cnt/offs; LDS permute; int4 COALESCED elist write.
__global__ __launch_bounds__(256) void k_sbsort(
    const unsigned* __restrict__ pbuf, const int* __restrict__ bbase,
    const int* __restrict__ total, int* __restrict__ cnt,
    int* __restrict__ offs, int* __restrict__ elist)
{
    __shared__ unsigned sin_[SCAP];
    __shared__ int sout_[SCAP];
    __shared__ int hist[SBK];
    __shared__ int cur[SBK];
    __shared__ int ts[256];
    int b = blockIdx.x, t = threadIdx.x;
    int base = bbase[b], n = total[b];
    if (n > SCAP) n = SCAP;             // safety clamp (never hit for this input)
    int nq = n >> 2;
    const uint4* p4 = (const uint4*)(pbuf + base);
    hist[t] = 0;
    __syncthreads();
    for (int i = t; i < nq; i += 256){
        uint4 q = p4[i];
        sin_[4*i]   = q.x; atomicAdd(&hist[q.x >> 17], 1);
        sin_[4*i+1] = q.y; atomicAdd(&hist[q.y >> 17], 1);
        sin_[4*i+2] = q.z; atomicAdd(&hist[q.z >> 17], 1);
        sin_[4*i+3] = q.w; atomicAdd(&hist[q.w >> 17], 1);
    }
    for (int i = (nq << 2) + t; i < n; i += 256){
        unsigned p = pbuf[base + i];
        sin_[i] = p;
        atomicAdd(&hist[p >> 17], 1);
    }
    __syncthreads();
    int h0 = hist[t];
    ts[t] = h0;
    __syncthreads();
    #pragma unroll
    for (int d = 1; d < 256; d <<= 1){
        int u = (t >= d) ? ts[t - d] : 0;
        __syncthreads();
        ts[t] += u;
        __syncthreads();
    }
    int e0 = ts[t] - h0;                // exclusive, LOCAL offset into sout
    cur[t] = e0;
    int g = b * SBK + t;
    if (g < NKEY){ cnt[g] = h0; offs[g] = base + e0; }
    __syncthreads();
    for (int i = t; i < n; i += 256){
        unsigned p = sin_[i];
        int pos = atomicAdd(&cur[p >> 17], 1);
        sout_[pos] = (int)(p & 0x1FFFFu);
    }
    __syncthreads();
    int4* o4 = (int4*)(elist + base);
    for (int i = t; i < nq; i += 256){
        int4 w;
        w.x = sout_[4*i]; w.y = sout_[4*i+1]; w.z = sout_[4*i+2]; w.w = sout_[4*i+3];
        o4[i] = w;
    }
    for (int i = (nq << 2) + t; i < n; i += 256) elist[base + i] = sout_[i];
}

// ---------------- MFMA edge pass: one wave per target node -------------------
// (round-9/13 proven form: simple loop, compiler-scheduled gathers)
__global__ __launch_bounds__(256) void k_edge_mfma(
    const _Float16* __restrict__ Pconst, const _Float16* __restrict__ Pvar,
    const int* __restrict__ offs, const int* __restrict__ cnt,
    const int* __restrict__ elist,
    const _Float16* __restrict__ w2hi, const _Float16* __restrict__ w2lo,
    const float* __restrict__ b1, const float* __restrict__ b2,
    float* __restrict__ accum, int n)
{
    int wid = (blockIdx.x * 256 + threadIdx.x) >> 6;
    int l   = threadIdx.x & 63;
    if (wid >= n) return;
    int row = l & 15;     // A-row (edge within tile) / C-col
    int kg  = l >> 4;     // k-chunk group

    f16x8 wh0 = ((const f16x8*)w2hi)[l];
    f16x8 wh1 = ((const f16x8*)w2hi)[64 + l];
    f16x8 wl0 = ((const f16x8*)w2lo)[l];
    f16x8 wl1 = ((const f16x8*)w2lo)[64 + l];
    float b2a = b2[row];
    float b2b = b2[16 + row];

    // pc16 = fp16(Pconst_row + b1), packed once per wave
    f16x8 pcv = *(const f16x8*)(Pconst + (size_t)wid * 32 + kg * 8);
    const float* pb = b1 + kg * 8;
    f16x8 pc16;
    #pragma unroll
    for (int j = 0; j < 8; j++) pc16[j] = (_Float16)((float)pcv[j] + pb[j]);
    const f16x8 zero = {};

    int start = offs[wid], deg = cnt[wid];
    float acc0 = 0.f, acc1 = 0.f;
    int nfull = deg >> 4;

    for (int t = 0; t < nfull; t++){
        int other = elist[start + t * 16 + row];
        f16x8 av = *(const f16x8*)(Pvar + (size_t)other * 32 + kg * 8);
        f16x8 h = __builtin_elementwise_max(av + pc16, zero);   // v_pk_add/max_f16

        f32x4 c0 = {0.f, 0.f, 0.f, 0.f}, c1 = {0.f, 0.f, 0.f, 0.f};
        c0 = __builtin_amdgcn_mfma_f32_16x16x32_f16(h, wh0, c0, 0, 0, 0);
        c0 = __builtin_amdgcn_mfma_f32_16x16x32_f16(h, wl0, c0, 0, 0, 0);
        c1 = __builtin_amdgcn_mfma_f32_16x16x32_f16(h, wh1, c1, 0, 0, 0);
        c1 = __builtin_amdgcn_mfma_f32_16x16x32_f16(h, wl1, c1, 0, 0, 0);

        #pragma unroll
        for (int rr = 0; rr < 4; rr++){
            acc0 += fmaxf(c0[rr] + b2a, 0.f);
            acc1 += fmaxf(c1[rr] + b2b, 0.f);
        }
    }
    if (deg & 15){                       // predicated tail tile
        int r  = nfull * 16 + row;
        int rc = (r < deg) ? r : (deg - 1);
        int other = elist[start + rc];
        f16x8 av = *(const f16x8*)(Pvar + (size_t)other * 32 + kg * 8);
        f16x8 h = __builtin_elementwise_max(av + pc16, zero);

        f32x4 c0 = {0.f, 0.f, 0.f, 0.f}, c1 = {0.f, 0.f, 0.f, 0.f};
        c0 = __builtin_amdgcn_mfma_f32_16x16x32_f16(h, wh0, c0, 0, 0, 0);
        c0 = __builtin_amdgcn_mfma_f32_16x16x32_f16(h, wl0, c0, 0, 0, 0);
        c1 = __builtin_amdgcn_mfma_f32_16x16x32_f16(h, wh1, c1, 0, 0, 0);
        c1 = __builtin_amdgcn_mfma_f32_16x16x32_f16(h, wl1, c1, 0, 0, 0);

        #pragma unroll
        for (int rr = 0; rr < 4; rr++){
            int er = nfull * 16 + kg * 4 + rr;   // C row = edge index
            if (er < deg){
                acc0 += fmaxf(c0[rr] + b2a, 0.f);
                acc1 += fmaxf(c1[rr] + b2b, 0.f);
            }
        }
    }

    acc0 += __shfl_xor(acc0, 16, 64);
    acc0 += __shfl_xor(acc0, 32, 64);
    acc1 += __shfl_xor(acc1, 16, 64);
    acc1 += __shfl_xor(acc1, 32, 64);

    if (l < 16)      accum[(size_t)wid * 32 + l] = acc0;       // cols 0..15
    else if (l < 32) accum[(size_t)wid * 32 + l] = acc1;       // cols 16..31
}

// ---------------- representation / output (thread-per-node, full ILP) --------

// out_c = relu(concat(acc, c) @ Wcr + bcr); write ONLY P = out_c @ W1c (fp16).
// (out_c itself is dead — nothing reads cemb after this.)
__global__ __launch_bounds__(256) void k_consrep_f(
    const float* __restrict__ acc, const _Float16* __restrict__ cemb,
    const float* __restrict__ Wcr, const float* __restrict__ bcr,
    const float* __restrict__ W1c, _Float16* __restrict__ P)
{
    int n = blockIdx.x * blockDim.x + threadIdx.x;
    if (n >= NC_N) return;
    float h[32];
    #pragma unroll
    for (int o = 0; o < 32; o++) h[o] = bcr[o];
    const float4* ap = (const float4*)(acc + (size_t)n * 32);
    #pragma unroll
    for (int q = 0; q < 8; q++){
        float4 t = ap[q];
        #pragma unroll
        for (int j = 0; j < 4; j++){
            float xk = (&t.x)[j];
            const float* w = Wcr + (q*4 + j)*32;
            #pragma unroll
            for (int o = 0; o < 32; o++) h[o] = fmaf(xk, w[o], h[o]);
        }
    }
    const f16x8* cp = (const f16x8*)(cemb + (size_t)n * 32);
    #pragma unroll
    for (int q = 0; q < 4; q++){
        f16x8 t = cp[q];
        #pragma unroll
        for (int j = 0; j < 8; j++){
            float xk = (float)t[j];
            const float* w = Wcr + (32 + q*8 + j)*32;
            #pragma unroll
            for (int o = 0; o < 32; o++) h[o] = fmaf(xk, w[o], h[o]);
        }
    }
    #pragma unroll
    for (int o = 0; o < 32; o++) h[o] = fmaxf(h[o], 0.f);
    float p[32];
    #pragma unroll
    for (int o = 0; o < 32; o++) p[o] = 0.f;
    #pragma unroll
    for (int k = 0; k < 32; k++){
        float hk = h[k];
        const float* w = W1c + k*32;
        #pragma unroll
        for (int o = 0; o < 32; o++) p[o] = fmaf(hk, w[o], p[o]);
    }
    f16x8* dp = (f16x8*)(P + (size_t)n * 32);
    #pragma unroll
    for (int q = 0; q < 4; q++){
        f16x8 r;
        #pragma unroll
        for (int j = 0; j < 8; j++) r[j] = (_Float16)p[q*8 + j];
        dp[q] = r;
    }
}

__global__ __launch_bounds__(256) void k_out(
    const float* __restrict__ acc, const _Float16* __restrict__ vemb,
    const float* __restrict__ Wvr, const float* __restrict__ bvr,
    const float* __restrict__ Wo1, const float* __restrict__ bo1,
    const float* __restrict__ Wo2, const float* __restrict__ bo2,
    const float* __restrict__ Wo3, const float* __restrict__ bo3,
    float* __restrict__ out)
{
    int n = blockIdx.x * blockDim.x + threadIdx.x;
    if (n >= NV_N) return;
    float a[32];
    #pragma unroll
    for (int o = 0; o < 32; o++) a[o] = bvr[o];
    const float4* ap = (const float4*)(acc + (size_t)n * 32);
    #pragma unroll
    for (int q = 0; q < 8; q++){
        float4 t = ap[q];
        #pragma unroll
        for (int j = 0; j < 4; j++){
            float xk = (&t.x)[j];
            const float* w = Wvr + (q*4 + j)*32;
            #pragma unroll
            for (int o = 0; o < 32; o++) a[o] = fmaf(xk, w[o], a[o]);
        }
    }
    const f16x8* vp = (const f16x8*)(vemb + (size_t)n * 32);
    #pragma unroll
    for (int q = 0; q < 4; q++){
        f16x8 t = vp[q];
        #pragma unroll
        for (int j = 0; j < 8; j++){
            float xk = (float)t[j];
            const float* w = Wvr + (32 + q*8 + j)*32;
            #pragma unroll
            for (int o = 0; o < 32; o++) a[o] = fmaf(xk, w[o], a[o]);
        }
    }
    #pragma unroll
    for (int o = 0; o < 32; o++) a[o] = fmaxf(a[o], 0.f);

    float c[32];
    #pragma unroll
    for (int o = 0; o < 32; o++) c[o] = bo1[o];
    #pragma unroll
    for (int k = 0; k < 32; k++){
        float ak = a[k];
        const float* w = Wo1 + k*32;
        #pragma unroll
        for (int o = 0; o < 32; o++) c[o] = fmaf(ak, w[o], c[o]);
    }
    #pragma unroll
    for (int o = 0; o < 32; o++) c[o] = fmaxf(c[o], 0.f);

    float d[32];
    #pragma unroll
    for (int o = 0; o < 32; o++) d[o] = bo2[o];
    #pragma unroll
    for (int k = 0; k < 32; k++){
        float ck = c[k];
        const float* w = Wo2 + k*32;
        #pragma unroll
        for (int o = 0; o < 32; o++) d[o] = fmaf(ck, w[o], d[o]);
    }
    float s = bo3[0];
    #pragma unroll
    for (int k = 0; k < 32; k++) s = fmaf(fmaxf(d[k], 0.f), Wo3[k], s);
    out[n] = s;
}

// ---------------- launch ----------------

extern "C" void kernel_launch(void* const* d_in, const int* in_sizes, int n_in,
                              void* d_out, int out_size, void* d_ws, size_t ws_size,
                              hipStream_t stream)
{
    (void)in_sizes; (void)n_in; (void)out_size; (void)ws_size;
    const float* consF = (const float*)d_in[0];
    const float* varsF = (const float*)d_in[1];
    const int*   eidx  = (const int*)d_in[2];
    const int*   eCons = eidx;
    const int*   eVars = eidx + E_N;

    const float* Wc  = (const float*)d_in[3],  *bc  = (const float*)d_in[4];
    const float* Wv  = (const float*)d_in[5],  *bv  = (const float*)d_in[6];
    const float* Wj1 = (const float*)d_in[7],  *bj1 = (const float*)d_in[8];
    const float* Wj2 = (const float*)d_in[9],  *bj2 = (const float*)d_in[10];
    const float* Wcr = (const float*)d_in[11], *bcr = (const float*)d_in[12];
    const float* Wvr = (const float*)d_in[13], *bvr = (const float*)d_in[14];
    const float* Wo1 = (const float*)d_in[15], *bo1 = (const float*)d_in[16];
    const float* Wo2 = (const float*)d_in[17], *bo2 = (const float*)d_in[18];
    const float* Wo3 = (const float*)d_in[19], *bo3 = (const float*)d_in[20];

    const size_t NT = (size_t)100000 * 32;
    _Float16* c_emb = (_Float16*)d_ws;          // 6.4 MB fp16
    _Float16* v_emb = c_emb + NT;               // 6.4 MB fp16
    _Float16* P1    = v_emb + NT;               // 6.4 MB fp16 (var pass1 / const pass2)
    _Float16* P2    = P1 + NT;                  // 6.4 MB fp16 (const pass1 / var pass2)
    float*    accum = (float*)(P2 + NT);        // 12.8 MB f32 segment sums
    unsigned* pbuf  = (unsigned*)P1;            // overlay 25.6MB+PAD over P1..accum+PAD
    int*   cnt     = (int*)(accum + NT) + PAD;  // [NKEY]  (PAD ints reserved for pbuf tail)
    int*   offs    = cnt + NKEY;                // [NKEY]
    int*   hists   = offs + NKEY;               // [NSB*NBLK_A]
    int*   partial = hists + NSB*NBLK_A;        // [NSB*NBLK_A]
    int*   total   = partial + NSB*NBLK_A;      // [NSB]
    int*   bbase   = total + NSB;               // [NSB]
    int*   elist   = bbase + NSB;               // [2E + PAD]
    _Float16* w2hi = (_Float16*)(elist + 2*E_N + PAD);  // [2][64][8]
    _Float16* w2lo = w2hi + 1024;

    const float* W1c = Wj1;                     // rows 0..31  (cons/out_c side)
    const float* W1v = Wj1 + 32*32;             // rows 32..63 (vars side)

    // --- deterministic 3-phase counting sort for BOTH directions ---
    k_sbhist<<<dim3(NBLK_A), dim3(256), 0, stream>>>(eCons, eVars, hists);
    k_scanA<<<dim3(NSB), dim3(512), 0, stream>>>(hists, partial, total);
    k_scanB_w2<<<dim3(1), dim3(1024), 0, stream>>>(total, bbase, Wj2, w2hi, w2lo);
    k_sbscatter<<<dim3(NBLK_A), dim3(256), 0, stream>>>(eCons, eVars, partial, bbase, pbuf);
    k_sbsort<<<dim3(NSB), dim3(256), 0, stream>>>(pbuf, bbase, total, cnt, offs, elist);

    // --- fused embeddings + layer-1 hoist (P1/P2 overwrite: pbuf is dead now) ---
    k_embed_all<<<dim3(782), dim3(256), 0, stream>>>(consF, varsF, Wc, bc, Wv, bv,
                                                     W1c, W1v, c_emb, v_emb, P2, P1);

    // ---- pass 1: edges -> constraints (keys [0,NC)) ----
    k_edge_mfma<<<dim3(25000), dim3(256), 0, stream>>>(
        P2, P1, offs, cnt, elist, w2hi, w2lo, bj1, bj2, accum, NC_N);
    k_consrep_f<<<dim3(391), dim3(256), 0, stream>>>(accum, c_emb, Wcr, bcr, W1c, P2);

    // ---- pass 2: edges -> variables (keys [NC,NC+NV)) ----
    k_edge_mfma<<<dim3(25000), dim3(256), 0, stream>>>(
        P1, P2, offs + NC_N, cnt + NC_N, elist, w2hi, w2lo, bj1, bj2, accum, NV_N);
    k_out<<<dim3(391), dim3(256), 0, stream>>>(accum, v_emb, Wvr, bvr,
                                               Wo1, bo1, Wo2, bo2, Wo3, bo3,
                                               (float*)d_out);
}

// Round 16
// 289.489 us; speedup vs baseline: 1.2431x; 1.0579x over previous
//
#include <hip/hip_runtime.h>

#define NC_N 100000
#define NV_N 100000
#define E_N  3200000
#define NKEY 200000          // unified key space: [0,NC) cons, [NC,NC+NV) vars
#define SBK  512             // keys per superbucket
#define NSB  391             // ceil(200000/512)
#define SCAP 18432           // per-superbucket capacity (mean 16368, sigma ~128)
#define NBLK_A 400
#define EPB4 2000            // int4 quads per phase-A block (400*2000*4 = E)
#define PAD  (16*NSB)        // base-padding slack for pbuf/elist

typedef __attribute__((ext_vector_type(8))) _Float16  f16x8;
typedef __attribute__((ext_vector_type(4))) float     f32x4;

// ---------------- fused node embedding (cons + vars in one grid) ----------------
// NOTE: must run AFTER k_sbsort — P1/P2 are overlaid by pbuf until then.

__global__ __launch_bounds__(256) void k_embed_all(
    const float* __restrict__ consF, const float* __restrict__ varsF,
    const float* __restrict__ Wc, const float* __restrict__ bc,
    const float* __restrict__ Wv, const float* __restrict__ bv,
    const float* __restrict__ W1c, const float* __restrict__ W1v,
    float* __restrict__ c_emb, float* __restrict__ v_emb,
    _Float16* __restrict__ Pc, _Float16* __restrict__ Pv)
{
    int n = blockIdx.x * blockDim.x + threadIdx.x;
    if (n < NC_N){
        float f0 = consF[2*(size_t)n], f1 = consF[2*(size_t)n + 1];
        float c[32];
        #pragma unroll
        for (int o = 0; o < 32; o++)
            c[o] = fmaxf(fmaf(f0, Wc[o], fmaf(f1, Wc[32 + o], bc[o])), 0.f);
        float4* dc = (float4*)(c_emb + (size_t)n * 32);
        #pragma unroll
        for (int q = 0; q < 8; q++){
            float4 r;
            #pragma unroll
            for (int j = 0; j < 4; j++) (&r.x)[j] = c[q*4 + j];
            dc[q] = r;
        }
        float p[32];
        #pragma unroll
        for (int o = 0; o < 32; o++) p[o] = 0.f;
        #pragma unroll
        for (int k = 0; k < 32; k++){
            float ck = c[k];
            const float* w = W1c + k*32;
            #pragma unroll
            for (int o = 0; o < 32; o++) p[o] = fmaf(ck, w[o], p[o]);
        }
        f16x8* dp = (f16x8*)(Pc + (size_t)n * 32);
        #pragma unroll
        for (int q = 0; q < 4; q++){
            f16x8 r;
            #pragma unroll
            for (int j = 0; j < 8; j++) r[j] = (_Float16)p[q*8 + j];
            dp[q] = r;
        }
    } else {
        int m = n - NC_N;
        if (m >= NV_N) return;
        float x[9];
        #pragma unroll
        for (int k = 0; k < 9; k++) x[k] = varsF[9*(size_t)m + k];
        float v[32];
        #pragma unroll
        for (int o = 0; o < 32; o++){
            float s = bv[o];
            #pragma unroll
            for (int k = 0; k < 9; k++) s = fmaf(x[k], Wv[k*32 + o], s);
            v[o] = fmaxf(s, 0.f);
        }
        float4* dv = (float4*)(v_emb + (size_t)m * 32);
        #pragma unroll
        for (int q = 0; q < 8; q++){
            float4 r;
            #pragma unroll
            for (int j = 0; j < 4; j++) (&r.x)[j] = v[q*4 + j];
            dv[q] = r;
        }
        float p[32];
        #pragma unroll
        for (int o = 0; o < 32; o++) p[o] = 0.f;
        #pragma unroll
        for (int k = 0; k < 32; k++){
            float vk = v[k];
            const float* w = W1v + k*32;
            #pragma unroll
            for (int o = 0; o < 32; o++) p[o] = fmaf(vk, w[o], p[o]);
        }
        f16x8* dp = (f16x8*)(Pv + (size_t)m * 32);
        #pragma unroll
        for (int q = 0; q < 4; q++){
            f16x8 r;
            #pragma unroll
            for (int j = 0; j < 8; j++) r[j] = (_Float16)p[q*8 + j];
            dp[q] = r;
        }
    }
}

// ---------------- deterministic 3-phase counting sort ----------------

// dual LDS hist copies (wave-pair parity) to halve same-bin atomic collisions
__global__ __launch_bounds__(256) void k_sbhist(
    const int* __restrict__ eC, const int* __restrict__ eV, int* __restrict__ hists)
{
    __shared__ int lh[2][NSB];
    int t = threadIdx.x, blk = blockIdx.x;
    int w = (t >> 6) & 1;
    for (int i = t; i < NSB; i += 256){ lh[0][i] = 0; lh[1][i] = 0; }
    __syncthreads();
    const int4* c4 = (const int4*)eC;
    const int4* v4 = (const int4*)eV;
    int qend = (blk + 1) * EPB4;
    for (int i = blk * EPB4 + t; i < qend; i += 256){
        int4 qc = c4[i];
        int4 qv = v4[i];
        #pragma unroll
        for (int j = 0; j < 4; j++){
            atomicAdd(&lh[w][(&qc.x)[j] >> 9], 1);
            atomicAdd(&lh[w][(NC_N + (&qv.x)[j]) >> 9], 1);
        }
    }
    __syncthreads();
    for (int i = t; i < NSB; i += 256) hists[i * NBLK_A + blk] = lh[0][i] + lh[1][i];
}

__global__ __launch_bounds__(512) void k_scanA(
    const int* __restrict__ hists, int* __restrict__ partial, int* __restrict__ total)
{
    __shared__ int s[512];
    int sb = blockIdx.x, t = threadIdx.x;
    int v = (t < NBLK_A) ? hists[sb * NBLK_A + t] : 0;
    s[t] = v;
    __syncthreads();
    #pragma unroll
    for (int d = 1; d < 512; d <<= 1){
        int u = (t >= d) ? s[t - d] : 0;
        __syncthreads();
        s[t] += u;
        __syncthreads();
    }
    if (t < NBLK_A) partial[sb * NBLK_A + t] = s[t] - v;   // exclusive
    if (t == 511) total[sb] = s[511];
}

// scan of PADDED superbucket totals -> 16-entry-aligned bbase; also W2 fp16 hi/lo prep
__global__ __launch_bounds__(512) void k_scanB_w2(
    const int* __restrict__ total, int* __restrict__ bbase,
    const float* __restrict__ W2, _Float16* __restrict__ w2hi, _Float16* __restrict__ w2lo)
{
    __shared__ int s[512];
    int t = threadIdx.x;
    int vp = (t < NSB) ? ((total[t] + 15) & ~15) : 0;
    s[t] = vp;
    __syncthreads();
    #pragma unroll
    for (int d = 1; d < 512; d <<= 1){
        int u = (t >= d) ? s[t - d] : 0;
        __syncthreads();
        s[t] += u;
        __syncthreads();
    }
    if (t < NSB) bbase[t] = s[t] - vp;
    if (t < 128){
        int h = t >> 6, l = t & 63;
        f16x8 vh, vl;
        #pragma unroll
        for (int j = 0; j < 8; j++){
            float w = W2[((l >> 4) * 8 + j) * 32 + h * 16 + (l & 15)];
            _Float16 hi = (_Float16)w;
            vh[j] = hi;
            vl[j] = (_Float16)(w - (float)hi);
        }
        ((f16x8*)w2hi)[t] = vh;
        ((f16x8*)w2lo)[t] = vl;
    }
}

// phase A3: single-writer runs per (block,superbucket); LDS atomics only
__global__ __launch_bounds__(256) void k_sbscatter(
    const int* __restrict__ eC, const int* __restrict__ eV,
    const int* __restrict__ partial, const int* __restrict__ bbase,
    unsigned* __restrict__ pbuf)
{
    __shared__ int lcur[NSB];
    int t = threadIdx.x, blk = blockIdx.x;
    for (int i = t; i < NSB; i += 256) lcur[i] = bbase[i] + partial[i * NBLK_A + blk];
    __syncthreads();
    const int4* c4 = (const int4*)eC;
    const int4* v4 = (const int4*)eV;
    int qend = (blk + 1) * EPB4;
    for (int i = blk * EPB4 + t; i < qend; i += 256){
        int4 qc = c4[i];
        int4 qv = v4[i];
        #pragma unroll
        for (int j = 0; j < 4; j++){
            int kc = (&qc.x)[j], kv = (&qv.x)[j];
            int p1 = atomicAdd(&lcur[kc >> 9], 1);
            pbuf[p1] = ((unsigned)(kc & 511) << 17) | (unsigned)kv;
            int gk = NC_N + kv;
            int p2 = atomicAdd(&lcur[gk >> 9], 1);
            pbuf[p2] = ((unsigned)(gk & 511) << 17) | (unsigned)kc;
        }
    }
}

// phase B: one block per superbucket; 512-bin hist/scan -> cnt/offs; LDS-staged
// permute; uint4 reads + int4 COALESCED elist write (bases 16-entry aligned).
__global__ __launch_bounds__(256) void k_sbsort(
    const unsigned* __restrict__ pbuf, const int* __restrict__ bbase,
    const int* __restrict__ total, int* __restrict__ cnt,
    int* __restrict__ offs, int* __restrict__ elist)
{
    __shared__ int sout[SCAP];
    __shared__ int hist[SBK];
    __shared__ int cur[SBK];
    __shared__ int ts[256];
    int b = blockIdx.x, t = threadIdx.x;
    int base = bbase[b], n = total[b];
    if (n > SCAP) n = SCAP;             // safety clamp (never hit for this input)
    int nq = n >> 2;
    const uint4* p4 = (const uint4*)(pbuf + base);
    for (int i = t; i < SBK; i += 256) hist[i] = 0;
    __syncthreads();
    for (int i = t; i < nq; i += 256){
        uint4 q = p4[i];
        atomicAdd(&hist[q.x >> 17], 1);
        atomicAdd(&hist[q.y >> 17], 1);
        atomicAdd(&hist[q.z >> 17], 1);
        atomicAdd(&hist[q.w >> 17], 1);
    }
    for (int i = (nq << 2) + t; i < n; i += 256) atomicAdd(&hist[pbuf[base + i] >> 17], 1);
    __syncthreads();
    int h0 = hist[2*t], h1 = hist[2*t+1];
    int tsum = h0 + h1;
    ts[t] = tsum;
    __syncthreads();
    #pragma unroll
    for (int d = 1; d < 256; d <<= 1){
        int u = (t >= d) ? ts[t - d] : 0;
        __syncthreads();
        ts[t] += u;
        __syncthreads();
    }
    int e0 = ts[t] - tsum;
    int e1 = e0 + h0;
    cur[2*t]   = e0;                    // LOCAL offsets into sout
    cur[2*t+1] = e1;
    int g = b * SBK + 2*t;
    if (g   < NKEY){ cnt[g]   = h0; offs[g]   = base + e0; }
    if (g+1 < NKEY){ cnt[g+1] = h1; offs[g+1] = base + e1; }
    __syncthreads();
    for (int i = t; i < nq; i += 256){
        uint4 q = p4[i];
        #pragma unroll
        for (int j = 0; j < 4; j++){
            unsigned p = (&q.x)[j];
            int pos = atomicAdd(&cur[p >> 17], 1);
            sout[pos] = (int)(p & 0x1FFFFu);
        }
    }
    for (int i = (nq << 2) + t; i < n; i += 256){
        unsigned p = pbuf[base + i];
        int pos = atomicAdd(&cur[p >> 17], 1);
        sout[pos] = (int)(p & 0x1FFFFu);
    }
    __syncthreads();
    int4* o4 = (int4*)(elist + base);
    for (int i = t; i < nq; i += 256){
        int4 w;
        w.x = sout[4*i]; w.y = sout[4*i+1]; w.z = sout[4*i+2]; w.w = sout[4*i+3];
        o4[i] = w;
    }
    for (int i = (nq << 2) + t; i < n; i += 256) elist[base + i] = sout[i];
}

// ---------------- MFMA edge pass: one wave per target node -------------------
// (round-9 proven form: simple loop, compiler-scheduled gathers)
// h_e = relu(pc16 + Pvar[other_e]) in PACKED fp16; G = H @ W2 via f16 MFMA with
// fp16 hi/lo weight split; acc[node][col] = sum_e relu(G[e][col] + b2[col]).
__global__ __launch_bounds__(256) void k_edge_mfma(
    const _Float16* __restrict__ Pconst, const _Float16* __restrict__ Pvar,
    const int* __restrict__ offs, const int* __restrict__ cnt,
    const int* __restrict__ elist,
    const _Float16* __restrict__ w2hi, const _Float16* __restrict__ w2lo,
    const float* __restrict__ b1, const float* __restrict__ b2,
    float* __restrict__ accum, int n)
{
    int wid = (blockIdx.x * 256 + threadIdx.x) >> 6;
    int l   = threadIdx.x & 63;
    if (wid >= n) return;
    int row = l & 15;     // A-row (edge within tile) / C-col
    int kg  = l >> 4;     // k-chunk group

    f16x8 wh0 = ((const f16x8*)w2hi)[l];
    f16x8 wh1 = ((const f16x8*)w2hi)[64 + l];
    f16x8 wl0 = ((const f16x8*)w2lo)[l];
    f16x8 wl1 = ((const f16x8*)w2lo)[64 + l];
    float b2a = b2[row];
    float b2b = b2[16 + row];

    // pc16 = fp16(Pconst_row + b1), packed once per wave
    f16x8 pcv = *(const f16x8*)(Pconst + (size_t)wid * 32 + kg * 8);
    const float* pb = b1 + kg * 8;
    f16x8 pc16;
    #pragma unroll
    for (int j = 0; j < 8; j++) pc16[j] = (_Float16)((float)pcv[j] + pb[j]);
    const f16x8 zero = {};

    int start = offs[wid], deg = cnt[wid];
    float acc0 = 0.f, acc1 = 0.f;
    int nfull = deg >> 4;

    for (int t = 0; t < nfull; t++){
        int other = elist[start + t * 16 + row];
        f16x8 av = *(const f16x8*)(Pvar + (size_t)other * 32 + kg * 8);
        f16x8 h = __builtin_elementwise_max(av + pc16, zero);   // v_pk_add/max_f16

        f32x4 c0 = {0.f, 0.f, 0.f, 0.f}, c1 = {0.f, 0.f, 0.f, 0.f};
        c0 = __builtin_amdgcn_mfma_f32_16x16x32_f16(h, wh0, c0, 0, 0, 0);
        c0 = __builtin_amdgcn_mfma_f32_16x16x32_f16(h, wl0, c0, 0, 0, 0);
        c1 = __builtin_amdgcn_mfma_f32_16x16x32_f16(h, wh1, c1, 0, 0, 0);
        c1 = __builtin_amdgcn_mfma_f32_16x16x32_f16(h, wl1, c1, 0, 0, 0);

        #pragma unroll
        for (int rr = 0; rr < 4; rr++){
            acc0 += fmaxf(c0[rr] + b2a, 0.f);
            acc1 += fmaxf(c1[rr] + b2b, 0.f);
        }
    }
    if (deg & 15){                       // predicated tail tile
        int r  = nfull * 16 + row;
        int rc = (r < deg) ? r : (deg - 1);
        int other = elist[start + rc];
        f16x8 av = *(const f16x8*)(Pvar + (size_t)other * 32 + kg * 8);
        f16x8 h = __builtin_elementwise_max(av + pc16, zero);

        f32x4 c0 = {0.f, 0.f, 0.f, 0.f}, c1 = {0.f, 0.f, 0.f, 0.f};
        c0 = __builtin_amdgcn_mfma_f32_16x16x32_f16(h, wh0, c0, 0, 0, 0);
        c0 = __builtin_amdgcn_mfma_f32_16x16x32_f16(h, wl0, c0, 0, 0, 0);
        c1 = __builtin_amdgcn_mfma_f32_16x16x32_f16(h, wh1, c1, 0, 0, 0);
        c1 = __builtin_amdgcn_mfma_f32_16x16x32_f16(h, wl1, c1, 0, 0, 0);

        #pragma unroll
        for (int rr = 0; rr < 4; rr++){
            int er = nfull * 16 + kg * 4 + rr;   // C row = edge index
            if (er < deg){
                acc0 += fmaxf(c0[rr] + b2a, 0.f);
                acc1 += fmaxf(c1[rr] + b2b, 0.f);
            }
        }
    }

    acc0 += __shfl_xor(acc0, 16, 64);
    acc0 += __shfl_xor(acc0, 32, 64);
    acc1 += __shfl_xor(acc1, 16, 64);
    acc1 += __shfl_xor(acc1, 32, 64);

    if (l < 16)      accum[(size_t)wid * 32 + l] = acc0;       // cols 0..15
    else if (l < 32) accum[(size_t)wid * 32 + l] = acc1;       // cols 16..31
}

// ---------------- fused representation / output ----------------

// out_c = relu(concat(acc, c) @ Wcr + bcr) -> cemb (in place) AND P = out_c @ W1c (fp16)
__global__ __launch_bounds__(256) void k_consrep_f(
    const float* __restrict__ acc, float* __restrict__ cemb,
    const float* __restrict__ Wcr, const float* __restrict__ bcr,
    const float* __restrict__ W1c, _Float16* __restrict__ P)
{
    int n = blockIdx.x * blockDim.x + threadIdx.x;
    if (n >= NC_N) return;
    float h[32];
    #pragma unroll
    for (int o = 0; o < 32; o++) h[o] = bcr[o];
    const float4* ap = (const float4*)(acc + (size_t)n * 32);
    #pragma unroll
    for (int q = 0; q < 8; q++){
        float4 t = ap[q];
        #pragma unroll
        for (int j = 0; j < 4; j++){
            float xk = (&t.x)[j];
            const float* w = Wcr + (q*4 + j)*32;
            #pragma unroll
            for (int o = 0; o < 32; o++) h[o] = fmaf(xk, w[o], h[o]);
        }
    }
    const float4* cp = (const float4*)(cemb + (size_t)n * 32);
    #pragma unroll
    for (int q = 0; q < 8; q++){
        float4 t = cp[q];
        #pragma unroll
        for (int j = 0; j < 4; j++){
            float xk = (&t.x)[j];
            const float* w = Wcr + (32 + q*4 + j)*32;
            #pragma unroll
            for (int o = 0; o < 32; o++) h[o] = fmaf(xk, w[o], h[o]);
        }
    }
    #pragma unroll
    for (int o = 0; o < 32; o++) h[o] = fmaxf(h[o], 0.f);
    float4* dst = (float4*)(cemb + (size_t)n * 32);
    #pragma unroll
    for (int q = 0; q < 8; q++){
        float4 r;
        #pragma unroll
        for (int j = 0; j < 4; j++) (&r.x)[j] = fmaxf(h[q*4 + j], 0.f);
        dst[q] = r;
    }
    float p[32];
    #pragma unroll
    for (int o = 0; o < 32; o++) p[o] = 0.f;
    #pragma unroll
    for (int k = 0; k < 32; k++){
        float hk = h[k];
        const float* w = W1c + k*32;
        #pragma unroll
        for (int o = 0; o < 32; o++) p[o] = fmaf(hk, w[o], p[o]);
    }
    f16x8* dp = (f16x8*)(P + (size_t)n * 32);
    #pragma unroll
    for (int q = 0; q < 4; q++){
        f16x8 r;
        #pragma unroll
        for (int j = 0; j < 8; j++) r[j] = (_Float16)p[q*8 + j];
        dp[q] = r;
    }
}

__global__ __launch_bounds__(256) void k_out(
    const float* __restrict__ acc, const float* __restrict__ vemb,
    const float* __restrict__ Wvr, const float* __restrict__ bvr,
    const float* __restrict__ Wo1, const float* __restrict__ bo1,
    const float* __restrict__ Wo2, const float* __restrict__ bo2,
    const float* __restrict__ Wo3, const float* __restrict__ bo3,
    float* __restrict__ out)
{
    int n = blockIdx.x * blockDim.x + threadIdx.x;
    if (n >= NV_N) return;
    float a[32];
    #pragma unroll
    for (int o = 0; o < 32; o++) a[o] = bvr[o];
    const float4* ap = (const float4*)(acc + (size_t)n * 32);
    #pragma unroll
    for (int q = 0; q < 8; q++){
        float4 t = ap[q];
        #pragma unroll
        for (int j = 0; j < 4; j++){
            float xk = (&t.x)[j];
            const float* w = Wvr + (q*4 + j)*32;
            #pragma unroll
            for (int o = 0; o < 32; o++) a[o] = fmaf(xk, w[o], a[o]);
        }
    }
    const float4* vp = (const float4*)(vemb + (size_t)n * 32);
    #pragma unroll
    for (int q = 0; q < 8; q++){
        float4 t = vp[q];
        #pragma unroll
        for (int j = 0; j < 4; j++){
            float xk = (&t.x)[j];
            const float* w = Wvr + (32 + q*4 + j)*32;
            #pragma unroll
            for (int o = 0; o < 32; o++) a[o] = fmaf(xk, w[o], a[o]);
        }
    }
    #pragma unroll
    for (int o = 0; o < 32; o++) a[o] = fmaxf(a[o], 0.f);

    float c[32];
    #pragma unroll
    for (int o = 0; o < 32; o++) c[o] = bo1[o];
    #pragma unroll
    for (int k = 0; k < 32; k++){
        float ak = a[k];
        const float* w = Wo1 + k*32;
        #pragma unroll
        for (int o = 0; o < 32; o++) c[o] = fmaf(ak, w[o], c[o]);
    }
    #pragma unroll
    for (int o = 0; o < 32; o++) c[o] = fmaxf(c[o], 0.f);

    float d[32];
    #pragma unroll
    for (int o = 0; o < 32; o++) d[o] = bo2[o];
    #pragma unroll
    for (int k = 0; k < 32; k++){
        float ck = c[k];
        const float* w = Wo2 + k*32;
        #pragma unroll
        for (int o = 0; o < 32; o++) d[o] = fmaf(ck, w[o], d[o]);
    }
    float s = bo3[0];
    #pragma unroll
    for (int k = 0; k < 32; k++) s = fmaf(fmaxf(d[k], 0.f), Wo3[k], s);
    out[n] = s;
}

// ---------------- launch ----------------

extern "C" void kernel_launch(void* const* d_in, const int* in_sizes, int n_in,
                              void* d_out, int out_size, void* d_ws, size_t ws_size,
                              hipStream_t stream)
{
    (void)in_sizes; (void)n_in; (void)out_size; (void)ws_size;
    const float* consF = (const float*)d_in[0];
    const float* varsF = (const float*)d_in[1];
    const int*   eidx  = (const int*)d_in[2];
    const int*   eCons = eidx;
    const int*   eVars = eidx + E_N;

    const float* Wc  = (const float*)d_in[3],  *bc  = (const float*)d_in[4];
    const float* Wv  = (const float*)d_in[5],  *bv  = (const float*)d_in[6];
    const float* Wj1 = (const float*)d_in[7],  *bj1 = (const float*)d_in[8];
    const float* Wj2 = (const float*)d_in[9],  *bj2 = (const float*)d_in[10];
    const float* Wcr = (const float*)d_in[11], *bcr = (const float*)d_in[12];
    const float* Wvr = (const float*)d_in[13], *bvr = (const float*)d_in[14];
    const float* Wo1 = (const float*)d_in[15], *bo1 = (const float*)d_in[16];
    const float* Wo2 = (const float*)d_in[17], *bo2 = (const float*)d_in[18];
    const float* Wo3 = (const float*)d_in[19], *bo3 = (const float*)d_in[20];

    const size_t NT = (size_t)100000 * 32;
    float*    c_emb = (float*)d_ws;             // 12.8 MB; -> out_c in place
    float*    v_emb = c_emb + NT;               // 12.8 MB
    _Float16* P1    = (_Float16*)(v_emb + NT);  // 6.4 MB fp16 (var pass1 / const pass2)
    _Float16* P2    = P1 + NT;                  // 6.4 MB fp16 (const pass1 / var pass2)
    float*    accum = (float*)(P2 + NT);        // 12.8 MB f32 segment sums
    unsigned* pbuf  = (unsigned*)P1;            // overlay 25.6MB+PAD over P1..accum+PAD
    int*   cnt     = (int*)(accum + NT) + PAD;  // [NKEY]  (PAD ints reserved for pbuf tail)
    int*   offs    = cnt + NKEY;                // [NKEY]
    int*   hists   = offs + NKEY;               // [NSB*NBLK_A]
    int*   partial = hists + NSB*NBLK_A;        // [NSB*NBLK_A]
    int*   total   = partial + NSB*NBLK_A;      // [NSB]
    int*   bbase   = total + NSB;               // [NSB]
    int*   elist   = bbase + NSB;               // [2E + PAD]
    _Float16* w2hi = (_Float16*)(elist + 2*E_N + PAD);  // [2][64][8]
    _Float16* w2lo = w2hi + 1024;

    const float* W1c = Wj1;                     // rows 0..31  (cons/out_c side)
    const float* W1v = Wj1 + 32*32;             // rows 32..63 (vars side)

    // --- deterministic 3-phase counting sort for BOTH directions ---
    k_sbhist<<<dim3(NBLK_A), dim3(256), 0, stream>>>(eCons, eVars, hists);
    k_scanA<<<dim3(NSB), dim3(512), 0, stream>>>(hists, partial, total);
    k_scanB_w2<<<dim3(1), dim3(512), 0, stream>>>(total, bbase, Wj2, w2hi, w2lo);
    k_sbscatter<<<dim3(NBLK_A), dim3(256), 0, stream>>>(eCons, eVars, partial, bbase, pbuf);
    k_sbsort<<<dim3(NSB), dim3(256), 0, stream>>>(pbuf, bbase, total, cnt, offs, elist);

    // --- fused embeddings + layer-1 hoist (P1/P2 overwrite: pbuf is dead now) ---
    k_embed_all<<<dim3(782), dim3(256), 0, stream>>>(consF, varsF, Wc, bc, Wv, bv,
                                                     W1c, W1v, c_emb, v_emb, P2, P1);

    // ---- pass 1: edges -> constraints (keys [0,NC)) ----
    k_edge_mfma<<<dim3(25000), dim3(256), 0, stream>>>(
        P2, P1, offs, cnt, elist, w2hi, w2lo, bj1, bj2, accum, NC_N);
    k_consrep_f<<<dim3(391), dim3(256), 0, stream>>>(accum, c_emb, Wcr, bcr, W1c, P2);

    // ---- pass 2: edges -> variables (keys [NC,NC+NV)) ----
    k_edge_mfma<<<dim3(25000), dim3(256), 0, stream>>>(
        P1, P2, offs + NC_N, cnt + NC_N, elist, w2hi, w2lo, bj1, bj2, accum, NV_N);
    k_out<<<dim3(391), dim3(256), 0, stream>>>(accum, v_emb, Wvr, bvr,
                                               Wo1, bo1, Wo2, bo2, Wo3, bo3,
                                               (float*)d_out);
}